// Round 19
// baseline (73.266 us; speedup 1.0000x reference)
//
#include <hip/hip_runtime.h>
#include <hip/hip_bf16.h>

#define NXX 256
#define NG 32768
#define WID 128

typedef short bf16x8 __attribute__((ext_vector_type(8)));
typedef float f32x4 __attribute__((ext_vector_type(4)));
typedef unsigned int u32x4 __attribute__((ext_vector_type(4)));

__device__ __forceinline__ unsigned short rne_bf16(float x) {
    unsigned int u = __float_as_uint(x);
    return (unsigned short)((u + 0x7fffu + ((u >> 16) & 1u)) >> 16);
}

// ---------------------------------------------------------------------------
// Prep (pi version, r7/r13-verified): W fragment streams, k-axis pre-permuted
// by pi: k=(kc:2|g:2|j2:1|j10:2) -> ch=(kc:2|j2:1|g:2|j10:2), so each layer's
// B-fragment is a direct cvt_pk pack of the thread's own D registers.
// Lane lv elem j of stream e=(l*4+kc)*8+nt holds W[pi][16nt+(lv&15)].
// ---------------------------------------------------------------------------
__global__ __launch_bounds__(64) void prep_kernel(
    const float* __restrict__ Wg, unsigned short* __restrict__ Bfrag) {
    const int e  = blockIdx.x;       // 0..127
    const int lv = threadIdx.x;      // 0..63
    const int l  = e >> 5;
    const int kc = (e >> 3) & 3;
    const int nt = e & 7;
    const int n  = nt * 16 + (lv & 15);
    const int g  = lv >> 4;          // k-granule 0..3
#pragma unroll
    for (int j = 0; j < 8; ++j) {
        const int ch = kc * 32 + ((j >> 2) << 4) + (g << 2) + (j & 3);  // pi
        float v = Wg[(size_t)l * 16384 + (size_t)ch * WID + n];
        Bfrag[(size_t)e * 512 + lv * 8 + j] = rne_bf16(v);
    }
}

__device__ __forceinline__ unsigned int pack_bf2(float a, float b) {
    union { __hip_bfloat162 h2; unsigned int u; } cv;
    cv.h2 = __float22bfloat162_rn(make_float2(a, b));   // low16 = a
    return cv.u;
}

union fragu { bf16x8 f; u32x4 u; };

// register-free async global->LDS copy; lds dest wave-uniform (HW adds lane*16)
#define GLOAD_LDS16(gsrc, ldst)                                              \
    __builtin_amdgcn_global_load_lds(                                        \
        (const __attribute__((address_space(1))) void*)(gsrc),               \
        (__attribute__((address_space(3))) void*)(ldst), 16, 0, 0)

// ---------------------------------------------------------------------------
// Fused net, r19 = r16 (r13 core + W in one 32KB LDS buffer) with the two
// counter-diagnosed codegen repairs:
//  (1) sched_group_barrier DS_READ(1)/MFMA(2) inside the MFMA loop — pins the
//      interleave so only 1-2 bh stay live (r16's VGPR 160 was scheduler
//      hoisting of all 32 ds_read results, NOT the dataflow; r13 proves the
//      live set fits in 124). NO launch_bounds (r15/r17: min-occupancy caps
//      strangle the allocator to 64 and spill ~0.4 GB).
//  (2) stage issue moved to sync -> ISSUE -> epilogue -> sync, so the ~900cy
//      epilogue hides the global_load_lds latency (r16 exposed it fully
//      between adjacent barriers).
// Mechanism target: Bfrag L1 traffic 2MB/CU -> 512KB/CU (W read once per
// block, shared by 4 waves via LDS); r14/r16 measured 1.64x per-wave-slot
// efficiency for W-in-LDS.
// ---------------------------------------------------------------------------
__global__ __launch_bounds__(256) void fused_kernel(
    const float* __restrict__ u0, const float* __restrict__ P,
    const float* __restrict__ W_in, const float* __restrict__ b_in,
    const unsigned short* __restrict__ Bfrag,
    const float* __restrict__ bg, const float* __restrict__ gamma,
    const float* __restrict__ beta, const float* __restrict__ W_out,
    const float* __restrict__ b_out, float* __restrict__ out)
{
    __shared__ __align__(16) char Wlds[32768];   // one layer of W fragments

    const int tid  = threadIdx.x;
    const int w    = tid >> 6;       // wave 0..3
    const int lane = tid & 63;
    const int l15  = lane & 15;
    const int lhi  = lane >> 4;      // 0..3

    const int blk  = blockIdx.x;     // 0..1023
    const int b    = blk >> 9;       // 0 or 1; partner batch = b+2
    const int ublk = (blk & 511) << 6;

    const int u  = ublk + 16 * w + l15;
    const int ix = u >> 7;
    const int t  = u & 127;

    const char* gB   = (const char*)Bfrag;        // layer l at offset l*32768
    const char* gSrc = gB + w * 8192 + lane * 16; // this wave's stage source
    char*       lDst = Wlds + w * 8192;           // this wave's stage dest

    // ---- issue layer-0 W staging immediately (hidden under X0 build) ----
#pragma unroll
    for (int i = 0; i < 8; ++i)
        GLOAD_LDS16(gSrc + i * 1024, lDst + i * 1024);

    // degree coeffs (t-major graph indexing), per-lane
    float c1, c2;
    {
        int gi = u & 255, gt = u >> 8;
        int d  = (gi > 0) + (gi < 255) + (gt > 0) + (gt < 127);
        float deg = 2.f * (float)d + 1.f;
        c1 = 2.f * (float)d * rsqrtf(deg);
        c2 = 1.f / deg;
    }

    // ---- features of node u for batch b (A) and b+2 (B) ----
    float featA[7], featB[7];
    {
        float s  = ((float)t + 0.5f) * 0.125f - 0.5f;
        float fs = floorf(s);
        int   t0 = (int)fs;
        float wt = s - fs;
        int t0c = t0 < 0 ? 0 : (t0 > 15 ? 15 : t0);
        int t1n = t0 + 1;
        int t1c = t1n < 0 ? 0 : (t1n > 15 ? 15 : t1n);
        const float* urA = u0 + ((size_t)b * NXX + ix) * 16;
        const float* urB = u0 + ((size_t)(b + 2) * NXX + ix) * 16;
        featA[0] = urA[t0c] * (1.f - wt) + urA[t1c] * wt;
        featB[0] = urB[t0c] * (1.f - wt) + urB[t1c] * wt;
#pragma unroll
        for (int f = 0; f < 4; ++f) {
            featA[1 + f] = P[b * 4 + f];
            featB[1 + f] = P[(b + 2) * 4 + f];
        }
        featA[5] = featB[5] = (float)ix * (1.f / 255.f);
        featA[6] = featB[6] = (float)t  * (1.f / 127.f);
    }

    // ---- X0 = feat @ W_in + b_in for both tiles (shared W_in loads) ----
    float xr0[8][4], xr1[8][4];
#pragma unroll
    for (int nt = 0; nt < 8; ++nt) {
        const int c = nt * 16 + 4 * lhi;
        float4 bi4 = *(const float4*)(b_in + c);
        float4 wf[7];
#pragma unroll
        for (int f = 0; f < 7; ++f) wf[f] = *(const float4*)(W_in + f * WID + c);
#pragma unroll
        for (int r = 0; r < 4; ++r) {
            float a0 = ((const float*)&bi4)[r];
            float a1 = a0;
#pragma unroll
            for (int f = 0; f < 7; ++f) {
                float wv = ((const float*)&wf[f])[r];
                a0 = fmaf(featA[f], wv, a0);
                a1 = fmaf(featB[f], wv, a1);
            }
            xr0[nt][r] = a0;
            xr1[nt][r] = a1;
        }
    }

    __syncthreads();   // implicit vmcnt(0) drain: layer-0 W resident in LDS

    const char* wl = Wlds + lane * 16;

    // ======== 4 GCN layers ========
    for (int l = 0; l < 4; ++l) {
        // ---- MFMA: kc-outer / nt-inner; W from LDS, X packed from regs ----
        // sched_group_barrier pins DS_READ(1) -> MFMA(2) per step: only 1-2
        // bh live => no VGPR inflation (the r16 failure mode).
        f32x4 acc0[8], acc1[8];
#pragma unroll
        for (int nt = 0; nt < 8; ++nt) {
            acc0[nt] = (f32x4){0.f, 0.f, 0.f, 0.f};
            acc1[nt] = (f32x4){0.f, 0.f, 0.f, 0.f};
        }
#pragma unroll
        for (int kc = 0; kc < 4; ++kc) {
            fragu x0f, x1f;
            x0f.u = (u32x4){pack_bf2(xr0[2 * kc][0],     xr0[2 * kc][1]),
                            pack_bf2(xr0[2 * kc][2],     xr0[2 * kc][3]),
                            pack_bf2(xr0[2 * kc + 1][0], xr0[2 * kc + 1][1]),
                            pack_bf2(xr0[2 * kc + 1][2], xr0[2 * kc + 1][3])};
            x1f.u = (u32x4){pack_bf2(xr1[2 * kc][0],     xr1[2 * kc][1]),
                            pack_bf2(xr1[2 * kc][2],     xr1[2 * kc][3]),
                            pack_bf2(xr1[2 * kc + 1][0], xr1[2 * kc + 1][1]),
                            pack_bf2(xr1[2 * kc + 1][2], xr1[2 * kc + 1][3])};
#pragma unroll
            for (int nt = 0; nt < 8; ++nt) {
                bf16x8 bh = *(const bf16x8*)(wl + (kc * 8 + nt) * 1024);
                acc0[nt] = __builtin_amdgcn_mfma_f32_16x16x32_bf16(bh, x0f.f, acc0[nt], 0, 0, 0);
                acc1[nt] = __builtin_amdgcn_mfma_f32_16x16x32_bf16(bh, x1f.f, acc1[nt], 0, 0, 0);
                __builtin_amdgcn_sched_group_barrier(0x100, 1, 0);  // 1 DS_READ
                __builtin_amdgcn_sched_group_barrier(0x008, 2, 0);  // 2 MFMA
            }
        }

        // ---- issue next layer's stage NOW; epilogue below hides it ----
        if (l < 3) {
            __syncthreads();             // all waves done reading W_l
#pragma unroll
            for (int i = 0; i < 8; ++i)
                GLOAD_LDS16(gSrc + (l + 1) * 32768 + i * 1024, lDst + i * 1024);
        }

        // ---- epilogue: REGISTER-LOCAL pair mix, +bg, LN, residual ReLU ----
        float s0 = 0.f, q0 = 0.f, s1 = 0.f, q1 = 0.f;
#pragma unroll
        for (int nt = 0; nt < 8; ++nt) {
            float4 bg4 = *(const float4*)(bg + l * WID + nt * 16 + 4 * lhi);
#pragma unroll
            for (int r = 0; r < 4; ++r) {
                float bgr = ((const float*)&bg4)[r];
                float h0 = acc0[nt][r];
                float h1 = acc1[nt][r];
                float a0 = h0 + bgr;                          // batch b (deg 1)
                float a1 = fmaf(c1, h0, fmaf(c2, h1, bgr));   // batch b+2
                acc0[nt][r] = a0;
                acc1[nt][r] = a1;
                s0 += a0;  q0 = fmaf(a0, a0, q0);
                s1 += a1;  q1 = fmaf(a1, a1, q1);
            }
        }
        s0 += __shfl_xor(s0, 16);  q0 += __shfl_xor(q0, 16);
        s1 += __shfl_xor(s1, 16);  q1 += __shfl_xor(q1, 16);
        s0 += __shfl_xor(s0, 32);  q0 += __shfl_xor(q0, 32);
        s1 += __shfl_xor(s1, 32);  q1 += __shfl_xor(q1, 32);
        float mu0 = s0 * (1.f / 128.f);
        float mu1 = s1 * (1.f / 128.f);
        float rs0 = rsqrtf(q0 * (1.f / 128.f) - mu0 * mu0 + 1e-5f);
        float rs1 = rsqrtf(q1 * (1.f / 128.f) - mu1 * mu1 + 1e-5f);
#pragma unroll
        for (int nt = 0; nt < 8; ++nt) {
            const int c = nt * 16 + 4 * lhi;
            float4 g4 = *(const float4*)(gamma + l * WID + c);
            float4 e4 = *(const float4*)(beta  + l * WID + c);
#pragma unroll
            for (int r = 0; r < 4; ++r) {
                float gv = ((const float*)&g4)[r];
                float ev = ((const float*)&e4)[r];
                float n0 = fmaf((acc0[nt][r] - mu0) * rs0, gv, ev);
                float n1 = fmaf((acc1[nt][r] - mu1) * rs1, gv, ev);
                xr0[nt][r] = fmaxf(n0 + xr0[nt][r], 0.f);
                xr1[nt][r] = fmaxf(n1 + xr1[nt][r], 0.f);
            }
        }

        if (l < 3) __syncthreads();   // implicit vmcnt drain: W_{l+1} ready
    }

    // ======== out head: two rows per lane ========
    float p0 = 0.f, p1 = 0.f;
#pragma unroll
    for (int nt = 0; nt < 8; ++nt) {
        float4 wo4 = *(const float4*)(W_out + nt * 16 + 4 * lhi);
#pragma unroll
        for (int r = 0; r < 4; ++r) {
            float wv = ((const float*)&wo4)[r];
            p0 = fmaf(xr0[nt][r], wv, p0);
            p1 = fmaf(xr1[nt][r], wv, p1);
        }
    }
    p0 += __shfl_xor(p0, 16);  p1 += __shfl_xor(p1, 16);
    p0 += __shfl_xor(p0, 32);  p1 += __shfl_xor(p1, 32);
    if (lhi == 0) {
        float bo = b_out[0];
        out[(size_t)b * NG + u]       = p0 + bo;
        out[(size_t)(b + 2) * NG + u] = p1 + bo;
    }
}

// ---------------------------------------------------------------------------
extern "C" void kernel_launch(void* const* d_in, const int* in_sizes, int n_in,
                              void* d_out, int out_size, void* d_ws, size_t ws_size,
                              hipStream_t stream) {
    const float* u0    = (const float*)d_in[0];
    const float* P     = (const float*)d_in[1];
    const float* W_in  = (const float*)d_in[2];
    const float* b_in  = (const float*)d_in[3];
    const float* Wg    = (const float*)d_in[4];
    const float* bg    = (const float*)d_in[5];
    const float* gamma = (const float*)d_in[6];
    const float* beta  = (const float*)d_in[7];
    const float* W_out = (const float*)d_in[8];
    const float* b_out = (const float*)d_in[9];

    unsigned short* Bfrag = (unsigned short*)d_ws;   // 128 KB

    prep_kernel<<<128, 64, 0, stream>>>(Wg, Bfrag);
    fused_kernel<<<1024, 256, 0, stream>>>(
        u0, P, W_in, b_in, Bfrag, bg, gamma, beta, W_out, b_out, (float*)d_out);
}

// Round 20
// 55.374 us; speedup vs baseline: 1.3231x; 1.3231x over previous
//
#include <hip/hip_runtime.h>
#include <hip/hip_bf16.h>

#define NXX 256
#define NG 32768
#define WID 128

typedef short bf16x8 __attribute__((ext_vector_type(8)));
typedef float f32x4 __attribute__((ext_vector_type(4)));
typedef unsigned int u32x4 __attribute__((ext_vector_type(4)));

__device__ __forceinline__ unsigned short rne_bf16(float x) {
    unsigned int u = __float_as_uint(x);
    return (unsigned short)((u + 0x7fffu + ((u >> 16) & 1u)) >> 16);
}

// ---------------------------------------------------------------------------
// Prep (pi version, r7/r13-verified): pack Wg into A-operand fragment
// streams with the k-axis PRE-PERMUTED by
//   pi: k=(kc:2|g:2|j2:1|j10:2) -> ch=(kc:2|j2:1|g:2|j10:2).
// GEMM is invariant under a common k-permutation of W and x; pi makes the
// B-fragment for k-chunk kc equal to a direct cvt_pk packing of the thread's
// own D registers xres[2kc..2kc+1][0..3] -> NO X LDS round trip.
// Lane lv elem j of stream e=(l*4+kc)*8+nt holds W[pi(kc,g,j)][16nt+(lv&15)].
// ---------------------------------------------------------------------------
__global__ __launch_bounds__(64) void prep_kernel(
    const float* __restrict__ Wg, unsigned short* __restrict__ Bfrag) {
    const int e  = blockIdx.x;       // 0..127
    const int lv = threadIdx.x;      // 0..63
    const int l  = e >> 5;
    const int kc = (e >> 3) & 3;
    const int nt = e & 7;
    const int n  = nt * 16 + (lv & 15);
    const int g  = lv >> 4;          // k-granule 0..3
#pragma unroll
    for (int j = 0; j < 8; ++j) {
        const int ch = kc * 32 + ((j >> 2) << 4) + (g << 2) + (j & 3);  // pi
        float v = Wg[(size_t)l * 16384 + (size_t)ch * WID + n];
        Bfrag[(size_t)e * 512 + lv * 8 + j] = rne_bf16(v);
    }
}

__device__ __forceinline__ unsigned int pack_bf2(float a, float b) {
    union { __hip_bfloat162 h2; unsigned int u; } cv;
    cv.h2 = __float22bfloat162_rn(make_float2(a, b));   // low16 = a
    return cv.u;
}

union fragu { bf16x8 f; u32x4 u; };

// ---------------------------------------------------------------------------
// FINAL (r13 champion, 55.2us measured): fully-fused net, no LDS, no
// barriers. Each wave owns 16 NODES (u = ublk+16w+(lane&15)), computes TWO
// MFMA tiles per layer (batch b and b+2) -> the batch-mixing graph epilogue
// is register-local (zero shuffles). kc-outer/nt-inner MFMA loop; B-frags
// built per-kc by 8 cvt_pk straight from the thread's own D registers via
// the pi k-permutation. VGPR 124 = exactly at the 128-unified-reg cliff;
// every pressure-positive or pressure-pinning variant (r10,r11,r14-r19)
// regressed -- see session notes. Residual stays fp32 (r18's bf16 residual
// cost +18us in unpack VALU).
// ---------------------------------------------------------------------------
__global__ __launch_bounds__(256) void fused_kernel(
    const float* __restrict__ u0, const float* __restrict__ P,
    const float* __restrict__ W_in, const float* __restrict__ b_in,
    const unsigned short* __restrict__ Bfrag,
    const float* __restrict__ bg, const float* __restrict__ gamma,
    const float* __restrict__ beta, const float* __restrict__ W_out,
    const float* __restrict__ b_out, float* __restrict__ out)
{
    const int tid  = threadIdx.x;
    const int w    = tid >> 6;
    const int lane = tid & 63;
    const int l15  = lane & 15;
    const int lhi  = lane >> 4;      // 0..3

    const int blk  = blockIdx.x;     // 0..1023
    const int b    = blk >> 9;       // 0 or 1; partner batch = b+2
    const int ublk = (blk & 511) << 6;

    const int u  = ublk + 16 * w + l15;
    const int ix = u >> 7;
    const int t  = u & 127;

    // degree coeffs (t-major graph indexing), per-lane
    float c1, c2;
    {
        int gi = u & 255, gt = u >> 8;
        int d  = (gi > 0) + (gi < 255) + (gt > 0) + (gt < 127);
        float deg = 2.f * (float)d + 1.f;
        c1 = 2.f * (float)d * rsqrtf(deg);
        c2 = 1.f / deg;
    }

    // ---- features of node u for batch b (A) and b+2 (B) ----
    float featA[7], featB[7];
    {
        float s  = ((float)t + 0.5f) * 0.125f - 0.5f;
        float fs = floorf(s);
        int   t0 = (int)fs;
        float wt = s - fs;
        int t0c = t0 < 0 ? 0 : (t0 > 15 ? 15 : t0);
        int t1n = t0 + 1;
        int t1c = t1n < 0 ? 0 : (t1n > 15 ? 15 : t1n);
        const float* urA = u0 + ((size_t)b * NXX + ix) * 16;
        const float* urB = u0 + ((size_t)(b + 2) * NXX + ix) * 16;
        featA[0] = urA[t0c] * (1.f - wt) + urA[t1c] * wt;
        featB[0] = urB[t0c] * (1.f - wt) + urB[t1c] * wt;
#pragma unroll
        for (int f = 0; f < 4; ++f) {
            featA[1 + f] = P[b * 4 + f];
            featB[1 + f] = P[(b + 2) * 4 + f];
        }
        featA[5] = featB[5] = (float)ix * (1.f / 255.f);
        featA[6] = featB[6] = (float)t  * (1.f / 127.f);
    }

    // ---- X0 = feat @ W_in + b_in for both tiles (shared W_in loads) ----
    float xr0[8][4], xr1[8][4];
#pragma unroll
    for (int nt = 0; nt < 8; ++nt) {
        const int c = nt * 16 + 4 * lhi;
        float4 bi4 = *(const float4*)(b_in + c);
        float4 wf[7];
#pragma unroll
        for (int f = 0; f < 7; ++f) wf[f] = *(const float4*)(W_in + f * WID + c);
#pragma unroll
        for (int r = 0; r < 4; ++r) {
            float a0 = ((const float*)&bi4)[r];
            float a1 = a0;
#pragma unroll
            for (int f = 0; f < 7; ++f) {
                float wv = ((const float*)&wf[f])[r];
                a0 = fmaf(featA[f], wv, a0);
                a1 = fmaf(featB[f], wv, a1);
            }
            xr0[nt][r] = a0;
            xr1[nt][r] = a1;
        }
    }

    // ======== 4 GCN layers (no LDS, no barriers) ========
    for (int l = 0; l < 4; ++l) {
        // ---- MFMA: kc-outer / nt-inner; fragments packed per-kc from regs --
        f32x4 acc0[8], acc1[8];
#pragma unroll
        for (int nt = 0; nt < 8; ++nt) {
            acc0[nt] = (f32x4){0.f, 0.f, 0.f, 0.f};
            acc1[nt] = (f32x4){0.f, 0.f, 0.f, 0.f};
        }
        const unsigned short* bp = Bfrag + (size_t)l * 16384 + lane * 8;
#pragma unroll
        for (int kc = 0; kc < 4; ++kc) {
            fragu x0f, x1f;
            x0f.u = (u32x4){pack_bf2(xr0[2 * kc][0],     xr0[2 * kc][1]),
                            pack_bf2(xr0[2 * kc][2],     xr0[2 * kc][3]),
                            pack_bf2(xr0[2 * kc + 1][0], xr0[2 * kc + 1][1]),
                            pack_bf2(xr0[2 * kc + 1][2], xr0[2 * kc + 1][3])};
            x1f.u = (u32x4){pack_bf2(xr1[2 * kc][0],     xr1[2 * kc][1]),
                            pack_bf2(xr1[2 * kc][2],     xr1[2 * kc][3]),
                            pack_bf2(xr1[2 * kc + 1][0], xr1[2 * kc + 1][1]),
                            pack_bf2(xr1[2 * kc + 1][2], xr1[2 * kc + 1][3])};
#pragma unroll
            for (int nt = 0; nt < 8; ++nt) {
                bf16x8 bh = *(const bf16x8*)(bp + (kc * 8 + nt) * 512);
                acc0[nt] = __builtin_amdgcn_mfma_f32_16x16x32_bf16(bh, x0f.f, acc0[nt], 0, 0, 0);
                acc1[nt] = __builtin_amdgcn_mfma_f32_16x16x32_bf16(bh, x1f.f, acc1[nt], 0, 0, 0);
            }
        }

        // ---- epilogue: REGISTER-LOCAL pair mix, +bg, LN, residual ReLU ----
        float s0 = 0.f, q0 = 0.f, s1 = 0.f, q1 = 0.f;
#pragma unroll
        for (int nt = 0; nt < 8; ++nt) {
            float4 bg4 = *(const float4*)(bg + l * WID + nt * 16 + 4 * lhi);
#pragma unroll
            for (int r = 0; r < 4; ++r) {
                float bgr = ((const float*)&bg4)[r];
                float h0 = acc0[nt][r];
                float h1 = acc1[nt][r];
                float a0 = h0 + bgr;                          // batch b (deg 1)
                float a1 = fmaf(c1, h0, fmaf(c2, h1, bgr));   // batch b+2
                acc0[nt][r] = a0;
                acc1[nt][r] = a1;
                s0 += a0;  q0 = fmaf(a0, a0, q0);
                s1 += a1;  q1 = fmaf(a1, a1, q1);
            }
        }
        s0 += __shfl_xor(s0, 16);  q0 += __shfl_xor(q0, 16);
        s1 += __shfl_xor(s1, 16);  q1 += __shfl_xor(q1, 16);
        s0 += __shfl_xor(s0, 32);  q0 += __shfl_xor(q0, 32);
        s1 += __shfl_xor(s1, 32);  q1 += __shfl_xor(q1, 32);
        float mu0 = s0 * (1.f / 128.f);
        float mu1 = s1 * (1.f / 128.f);
        float rs0 = rsqrtf(q0 * (1.f / 128.f) - mu0 * mu0 + 1e-5f);
        float rs1 = rsqrtf(q1 * (1.f / 128.f) - mu1 * mu1 + 1e-5f);
#pragma unroll
        for (int nt = 0; nt < 8; ++nt) {
            const int c = nt * 16 + 4 * lhi;
            float4 g4 = *(const float4*)(gamma + l * WID + c);
            float4 e4 = *(const float4*)(beta  + l * WID + c);
#pragma unroll
            for (int r = 0; r < 4; ++r) {
                float gv = ((const float*)&g4)[r];
                float ev = ((const float*)&e4)[r];
                float n0 = fmaf((acc0[nt][r] - mu0) * rs0, gv, ev);
                float n1 = fmaf((acc1[nt][r] - mu1) * rs1, gv, ev);
                xr0[nt][r] = fmaxf(n0 + xr0[nt][r], 0.f);
                xr1[nt][r] = fmaxf(n1 + xr1[nt][r], 0.f);
            }
        }
    }

    // ======== out head: two rows per lane ========
    float p0 = 0.f, p1 = 0.f;
#pragma unroll
    for (int nt = 0; nt < 8; ++nt) {
        float4 wo4 = *(const float4*)(W_out + nt * 16 + 4 * lhi);
#pragma unroll
        for (int r = 0; r < 4; ++r) {
            float wv = ((const float*)&wo4)[r];
            p0 = fmaf(xr0[nt][r], wv, p0);
            p1 = fmaf(xr1[nt][r], wv, p1);
        }
    }
    p0 += __shfl_xor(p0, 16);  p1 += __shfl_xor(p1, 16);
    p0 += __shfl_xor(p0, 32);  p1 += __shfl_xor(p1, 32);
    if (lhi == 0) {
        float bo = b_out[0];
        out[(size_t)b * NG + u]       = p0 + bo;
        out[(size_t)(b + 2) * NG + u] = p1 + bo;
    }
}

// ---------------------------------------------------------------------------
extern "C" void kernel_launch(void* const* d_in, const int* in_sizes, int n_in,
                              void* d_out, int out_size, void* d_ws, size_t ws_size,
                              hipStream_t stream) {
    const float* u0    = (const float*)d_in[0];
    const float* P     = (const float*)d_in[1];
    const float* W_in  = (const float*)d_in[2];
    const float* b_in  = (const float*)d_in[3];
    const float* Wg    = (const float*)d_in[4];
    const float* bg    = (const float*)d_in[5];
    const float* gamma = (const float*)d_in[6];
    const float* beta  = (const float*)d_in[7];
    const float* W_out = (const float*)d_in[8];
    const float* b_out = (const float*)d_in[9];

    unsigned short* Bfrag = (unsigned short*)d_ws;   // 128 KB

    prep_kernel<<<128, 64, 0, stream>>>(Wg, Bfrag);
    fused_kernel<<<1024, 256, 0, stream>>>(
        u0, P, W_in, b_in, Bfrag, bg, gamma, beta, W_out, b_out, (float*)d_out);
}